// Round 1
// baseline (102.301 us; speedup 1.0000x reference)
//
#include <hip/hip_runtime.h>

// SwarmNet: N=128 samples(=agents), T=100, D=4, H=32, Tp=94.
// Round-8: occupancy fix. Both kernels were latency-bound at ~1 block/CU
// (k_conv: 256 blocks x 256 thr = 1 wave/SIMD; k_agg: 376 blocks = 1.47/CU).
// k_conv: same grid (128,2) (no halo growth) but 512 threads -> 8 waves/CU,
//         per-thread serial LDS/L2 chain halved.
// k_agg:  i-slice 32->16, grid (94,8) = 752 blocks ~= 3 blocks/CU (~12 waves/CU).

#define NN 128
#define TT 100
#define TP 94
#define HH 32

__global__ __launch_bounds__(512) void k_conv(
    const float* __restrict__ x,
    const float* __restrict__ w1, const float* __restrict__ b1,
    const float* __restrict__ w2, const float* __restrict__ b2,
    const float* __restrict__ w3, const float* __restrict__ b3,
    const float* __restrict__ We,
    float* __restrict__ h_g, float* __restrict__ ej_g, float* __restrict__ ei_g)
{
    __shared__ float sx[4][72];    // x cols [t0g, t0g+54), zero-padded to 72
    __shared__ float s1[16][68];   // conv1 out (valid t<52)
    __shared__ float s2[32][64];   // conv2 out (valid t<50)
    __shared__ float s3[32][48];   // conv3 out (valid t<48)

    const int n    = blockIdx.x;
    const int half = blockIdx.y;
    const int t0g  = half * 46;    // out t-range [t0g, t0g+48); halves overlap at 46,47
    const int tid  = threadIdx.x;

    // stage x: 54 float4 columns; zero-fill pad columns
    if (tid < 72) {
        float4 v = make_float4(0.f, 0.f, 0.f, 0.f);
        if (tid < 54) v = ((const float4*)x)[n * TT + t0g + tid];
        sx[0][tid] = v.x; sx[1][tid] = v.y; sx[2][tid] = v.z; sx[3][tid] = v.w;
    }
    __syncthreads();

    // conv1: (4,.) -> (16,.), 16*68 outputs, flat over 512 threads
    for (int idx = tid; idx < 16 * 68; idx += 512) {
        int o = idx / 68, t = idx - o * 68;
        float acc = b1[o];
        #pragma unroll
        for (int i = 0; i < 4; ++i)
            #pragma unroll
            for (int k = 0; k < 3; ++k)
                acc += sx[i][t + k] * w1[o * 12 + i * 3 + k];
        s1[o][t] = fmaxf(acc, 0.f);
    }
    __syncthreads();

    // conv2: (16,.) -> (32,64). thread = (o=tid&31, seg=tid>>5 of 16), 4 t each
    {
        const int o = tid & 31, seg = tid >> 5;
        const int t0 = seg * 4;
        float acc[4];
        float bv = b2[o];
        #pragma unroll
        for (int u = 0; u < 4; ++u) acc[u] = bv;
        #pragma unroll
        for (int i = 0; i < 16; ++i) {
            float4 f0 = *(const float4*)&s1[i][t0];
            float4 f1 = *(const float4*)&s1[i][t0 + 4];
            float a[8] = {f0.x, f0.y, f0.z, f0.w, f1.x, f1.y, f1.z, f1.w};
            float W0 = w2[o * 48 + i * 3 + 0];
            float W1 = w2[o * 48 + i * 3 + 1];
            float W2 = w2[o * 48 + i * 3 + 2];
            #pragma unroll
            for (int u = 0; u < 4; ++u)
                acc[u] += a[u] * W0 + a[u + 1] * W1 + a[u + 2] * W2;
        }
        #pragma unroll
        for (int u = 0; u < 4; ++u) s2[o][t0 + u] = fmaxf(acc[u], 0.f);
    }
    __syncthreads();

    // conv3: (32,.) -> (32,48). thread = (o=tid&31, seg=tid>>5<12), 4 t each.
    // Writes s3 (for proj) and h_g directly from registers (coalesced 128B runs).
    {
        const int o = tid & 31, seg = tid >> 5;
        if (seg < 12) {
            const int t0 = seg * 4;
            float acc[4];
            float bv = b3[o];
            #pragma unroll
            for (int u = 0; u < 4; ++u) acc[u] = bv;
            #pragma unroll
            for (int i = 0; i < 32; ++i) {
                float4 f0 = *(const float4*)&s2[i][t0];
                float4 f1 = *(const float4*)&s2[i][t0 + 4];
                float a[8] = {f0.x, f0.y, f0.z, f0.w, f1.x, f1.y, f1.z, f1.w};
                float W0 = w3[o * 96 + i * 3 + 0];
                float W1 = w3[o * 96 + i * 3 + 1];
                float W2 = w3[o * 96 + i * 3 + 2];
                #pragma unroll
                for (int u = 0; u < 4; ++u)
                    acc[u] += a[u] * W0 + a[u + 1] * W1 + a[u + 2] * W2;
            }
            #pragma unroll
            for (int u = 0; u < 4; ++u) {
                float v = fmaxf(acc[u], 0.f);
                s3[o][t0 + u] = v;
                h_g[((t0g + t0 + u) * NN + n) * HH + o] = v;
            }
        }
    }
    __syncthreads();

    // proj: ej = h@We[:32], ei = h@We[32:]. thread = (d=tid&31, seg=tid>>5<12), 4 t
    {
        const int d = tid & 31, seg = tid >> 5;
        if (seg < 12) {
            const int t0 = seg * 4;
            float aj[4], ai[4];
            #pragma unroll
            for (int u = 0; u < 4; ++u) { aj[u] = 0.f; ai[u] = 0.f; }
            #pragma unroll
            for (int c = 0; c < 32; ++c) {
                float4 f0 = *(const float4*)&s3[c][t0];
                float hv[4] = {f0.x, f0.y, f0.z, f0.w};
                float wj = We[c * 32 + d];
                float wi = We[(32 + c) * 32 + d];
                #pragma unroll
                for (int u = 0; u < 4; ++u) {
                    aj[u] += hv[u] * wj;
                    ai[u] += hv[u] * wi;
                }
            }
            #pragma unroll
            for (int u = 0; u < 4; ++u) {
                int tg = t0g + t0 + u;
                ej_g[(tg * NN + n) * HH + d] = aj[u];
                ei_g[(tg * NN + n) * HH + d] = ai[u];
            }
        }
    }
}

__global__ __launch_bounds__(256) void k_agg(
    const float* __restrict__ x,
    const float* __restrict__ h_g, const float* __restrict__ ej_g,
    const float* __restrict__ ei_g,
    const float* __restrict__ be, const float* __restrict__ Wa,
    const float* __restrict__ ba, const float* __restrict__ Wu,
    const float* __restrict__ bu, const float* __restrict__ Wd,
    const float* __restrict__ bd, float* __restrict__ out)
{
    const int t  = blockIdx.x;  // 0..93
    const int ib = blockIdx.y;  // 0..7 (i-slice of 16 agents)
    const int tid = threadIdx.x;

    __shared__ float sej[NN * HH];     // 16 KB: ej for ALL 128 agents at this t
    __shared__ float sei[16 * HH];
    __shared__ float sh[16 * HH];
    __shared__ float sagg[16 * HH];
    __shared__ float sagg2[16 * HH];
    __shared__ float supd[16 * HH];

    // stage ej[t,:,:] (16 KB) + ei/h slices, vectorized
    {
        const float4* ej4 = (const float4*)(ej_g + t * NN * HH);
        float4* s4 = (float4*)sej;
        #pragma unroll
        for (int u = 0; u < 4; ++u) s4[tid + 256 * u] = ej4[tid + 256 * u];
        if (tid < 128) {
            const float4* ei4 = (const float4*)(ei_g + (t * NN + ib * 16) * HH);
            const float4* h4  = (const float4*)(h_g  + (t * NN + ib * 16) * HH);
            ((float4*)sei)[tid] = ei4[tid];
            ((float4*)sh)[tid]  = h4[tid];
        }
    }
    __syncthreads();

    const int d  = tid & 31;
    const int i0 = tid >> 5;  // thread owns i = i0 + 8u, u<2

    // agg[i,d] = sum_j relu(ej[j,d] + ei[i,d] + be[d]) - diag
    {
        float bev = be[d];
        float c[2], acc[2];
        #pragma unroll
        for (int u = 0; u < 2; ++u) {
            int i = i0 + u * 8;
            c[u] = sei[i * HH + d] + bev;
            acc[u] = -fmaxf(sej[(ib * 16 + i) * HH + d] + c[u], 0.f);
        }
        #pragma unroll 8
        for (int j = 0; j < NN; ++j) {
            float v = sej[j * HH + d];   // broadcast across lanes sharing d
            #pragma unroll
            for (int u = 0; u < 2; ++u)
                acc[u] += fmaxf(v + c[u], 0.f);
        }
        #pragma unroll
        for (int u = 0; u < 2; ++u)
            sagg[(i0 + u * 8) * HH + d] = acc[u];
    }
    __syncthreads();

    // agg2 = relu(agg @ Wa + ba)
    {
        float acc[2];
        float bav = ba[d];
        #pragma unroll
        for (int u = 0; u < 2; ++u) acc[u] = bav;
        #pragma unroll
        for (int c = 0; c < 32; ++c) {
            float wa = Wa[c * 32 + d];
            #pragma unroll
            for (int u = 0; u < 2; ++u)
                acc[u] += sagg[(i0 + u * 8) * HH + c] * wa;
        }
        #pragma unroll
        for (int u = 0; u < 2; ++u)
            sagg2[(i0 + u * 8) * HH + d] = fmaxf(acc[u], 0.f);
    }
    __syncthreads();

    // upd = relu(h @ Wu[:32] + agg2 @ Wu[32:] + bu)
    {
        float acc[2];
        float buv = bu[d];
        #pragma unroll
        for (int u = 0; u < 2; ++u) acc[u] = buv;
        #pragma unroll
        for (int c = 0; c < 32; ++c) {
            float wh = Wu[c * 32 + d];
            float wg = Wu[(32 + c) * 32 + d];
            #pragma unroll
            for (int u = 0; u < 2; ++u) {
                int i = i0 + u * 8;
                acc[u] += sh[i * HH + c] * wh + sagg2[i * HH + c] * wg;
            }
        }
        #pragma unroll
        for (int u = 0; u < 2; ++u)
            supd[(i0 + u * 8) * HH + d] = fmaxf(acc[u], 0.f);
    }
    __syncthreads();

    // dec = upd @ Wd + bd; out[n,t,:] = x[n,6+t,:] + dec
    if (tid < 64) {
        int i = tid >> 2, d4 = tid & 3;
        int n = ib * 16 + i;
        float a = bd[d4];
        #pragma unroll
        for (int c = 0; c < 32; ++c)
            a += supd[i * HH + c] * Wd[c * 4 + d4];
        out[n * (TP * 4) + t * 4 + d4] = x[n * (TT * 4) + (6 + t) * 4 + d4] + a;
    }
}

extern "C" void kernel_launch(void* const* d_in, const int* in_sizes, int n_in,
                              void* d_out, int out_size, void* d_ws, size_t ws_size,
                              hipStream_t stream) {
    const float* x  = (const float*)d_in[0];
    const float* w1 = (const float*)d_in[1];
    const float* b1 = (const float*)d_in[2];
    const float* w2 = (const float*)d_in[3];
    const float* b2 = (const float*)d_in[4];
    const float* w3 = (const float*)d_in[5];
    const float* b3 = (const float*)d_in[6];
    const float* We = (const float*)d_in[7];
    const float* be = (const float*)d_in[8];
    const float* Wa = (const float*)d_in[9];
    const float* ba = (const float*)d_in[10];
    const float* Wu = (const float*)d_in[11];
    const float* bu = (const float*)d_in[12];
    const float* Wd = (const float*)d_in[13];
    const float* bd = (const float*)d_in[14];

    float* ws   = (float*)d_ws;
    float* h_g  = ws;                      // 94*128*32
    float* ej_g = ws + TP * NN * HH;       // 94*128*32
    float* ei_g = ws + 2 * TP * NN * HH;   // 94*128*32

    k_conv<<<dim3(NN, 2), 512, 0, stream>>>(x, w1, b1, w2, b2, w3, b3, We,
                                            h_g, ej_g, ei_g);
    k_agg<<<dim3(TP, 8), 256, 0, stream>>>(x, h_g, ej_g, ei_g,
                                           be, Wa, ba, Wu, bu, Wd, bd,
                                           (float*)d_out);
}